// Round 1
// baseline (465.908 us; speedup 1.0000x reference)
//
#include <hip/hip_runtime.h>
#include <cstdint>
#include <cstddef>

#define B_ 8
#define S_ 2048
#define D_ 512

typedef __attribute__((ext_vector_type(8))) short short8;
typedef __attribute__((ext_vector_type(4))) float f32x4;

// f32 -> bf16 round-to-nearest-even
__device__ inline unsigned short f2bf(float f) {
  unsigned u = __float_as_uint(f);
  u += 0x7FFFu + ((u >> 16) & 1u);
  return (unsigned short)(u >> 16);
}

__global__ void convert_kernel(const float* __restrict__ x,
                               unsigned short* __restrict__ xb, int n4) {
  const float4* x4 = (const float4*)x;
  ushort4* o4 = (ushort4*)xb;
  for (int i = blockIdx.x * blockDim.x + threadIdx.x; i < n4;
       i += gridDim.x * blockDim.x) {
    float4 v = x4[i];
    ushort4 o;
    o.x = f2bf(v.x); o.y = f2bf(v.y); o.z = f2bf(v.z); o.w = f2bf(v.w);
    o4[i] = o;
  }
}

#define GLDS(g, l) __builtin_amdgcn_global_load_lds( \
    (const __attribute__((address_space(1))) void*)(g), \
    (__attribute__((address_space(3))) void*)(l), 16, 0, 0)

// C = X * X^T tile (128x128), fused exp(exp(s)/sqrt(D)) + mask, unnormalized
// write + row-sum atomics into Z.
__global__ __launch_bounds__(256) void gemm_exp_kernel(
    const unsigned short* __restrict__ xb, const int* __restrict__ mask,
    float* __restrict__ pbuf, float* __restrict__ Z) {
  __shared__ unsigned short At[128 * 64];
  __shared__ unsigned short Bt[128 * 64];
  const int b = blockIdx.z;
  const int qt = blockIdx.y;
  const int kt = blockIdx.x;
  const int tid = threadIdx.x;
  const int wid = tid >> 6;
  const int lane = tid & 63;

  const unsigned short* xbat = xb + (size_t)b * S_ * D_;
  const unsigned short* aglob = xbat + (size_t)qt * 128 * D_;
  const unsigned short* bglob = xbat + (size_t)kt * 128 * D_;

  f32x4 acc[4][4] = {};

  const int wr = (wid >> 1) * 64;   // wave row offset within 128-tile
  const int wc = (wid & 1) * 64;    // wave col offset
  const int lrow = lane & 15;
  const int lk = (lane >> 4) * 8;

  for (int k0 = 0; k0 < D_; k0 += 64) {
    __syncthreads();  // protect LDS from previous iteration's readers
    #pragma unroll
    for (int i = 0; i < 4; i++) {
      int chunk = i * 256 + tid;    // 0..1023, 16B chunks; wave-linear in LDS
      int row = chunk >> 3;         // 8 chunks per 64-col row
      int col = (chunk & 7) * 8;
      GLDS(aglob + row * D_ + k0 + col, &At[chunk * 8]);
      GLDS(bglob + row * D_ + k0 + col, &Bt[chunk * 8]);
    }
    __syncthreads();  // drains vmcnt -> LDS tiles valid
    #pragma unroll
    for (int ks = 0; ks < 64; ks += 32) {
      short8 av[4], bv[4];
      #pragma unroll
      for (int m = 0; m < 4; m++)
        av[m] = *(const short8*)&At[(wr + m * 16 + lrow) * 64 + ks + lk];
      #pragma unroll
      for (int n = 0; n < 4; n++)
        bv[n] = *(const short8*)&Bt[(wc + n * 16 + lrow) * 64 + ks + lk];
      #pragma unroll
      for (int m = 0; m < 4; m++)
        #pragma unroll
        for (int n = 0; n < 4; n++)
          acc[m][n] = __builtin_amdgcn_mfma_f32_16x16x32_bf16(
              av[m], bv[n], acc[m][n], 0, 0, 0);
    }
  }

  const float inv_sqrt_d = 0.04419417382415922f;  // 1/sqrt(512)
  const int qbase = qt * 128 + wr;
  const int kbase = kt * 128 + wc;
  const int* mbat = mask + (size_t)b * S_ * S_;
  float* pbat = pbuf + (size_t)b * S_ * S_;
  float* Zb = Z + b * S_;

  #pragma unroll
  for (int m = 0; m < 4; m++) {
    float rsum[4] = {0.f, 0.f, 0.f, 0.f};
    #pragma unroll
    for (int r = 0; r < 4; r++) {
      const int row = qbase + m * 16 + (lane >> 4) * 4 + r;
      #pragma unroll
      for (int n = 0; n < 4; n++) {
        const int col = kbase + n * 16 + (lane & 15);
        float s = acc[m][n][r];
        float u = 0.0f;
        if (mbat[(size_t)row * S_ + col] != 0)
          u = __expf(__expf(s) * inv_sqrt_d);  // exp(scores), scores=exp(s)/sqrt(D)
        pbat[(size_t)row * S_ + col] = u;      // unnormalized
        rsum[r] += u;
      }
    }
    // reduce across the 16 lanes sharing a row (lane&15 spans cols)
    #pragma unroll
    for (int r = 0; r < 4; r++) {
      float v = rsum[r];
      v += __shfl_xor(v, 1);
      v += __shfl_xor(v, 2);
      v += __shfl_xor(v, 4);
      v += __shfl_xor(v, 8);
      if ((lane & 15) == 0)
        atomicAdd(&Zb[qbase + m * 16 + (lane >> 4) * 4 + r], v);
    }
  }
}

// p = u / Z (row-wise), accumulate column sums cs[b,k] = sum_q p[b,q,k].
__global__ __launch_bounds__(256) void norm_colsum_kernel(
    float* __restrict__ p, const float* __restrict__ Z, float* __restrict__ cs) {
  const int b = blockIdx.y;
  const int q0 = blockIdx.x * 16;
  const int t = threadIdx.x;
  float4* prow = (float4*)(p + ((size_t)b * S_ + q0) * S_);
  const float* Zb = Z + b * S_ + q0;
  float a0x = 0, a0y = 0, a0z = 0, a0w = 0;
  float a1x = 0, a1y = 0, a1z = 0, a1w = 0;
  for (int r = 0; r < 16; r++) {
    float invZ = 1.0f / Zb[r];
    float4 u0 = prow[r * 512 + t];
    float4 u1 = prow[r * 512 + t + 256];
    u0.x *= invZ; u0.y *= invZ; u0.z *= invZ; u0.w *= invZ;
    u1.x *= invZ; u1.y *= invZ; u1.z *= invZ; u1.w *= invZ;
    prow[r * 512 + t] = u0;
    prow[r * 512 + t + 256] = u1;
    a0x += u0.x; a0y += u0.y; a0z += u0.z; a0w += u0.w;
    a1x += u1.x; a1y += u1.y; a1z += u1.z; a1w += u1.w;
  }
  float* csb = cs + b * S_;
  atomicAdd(&csb[4 * t + 0], a0x);
  atomicAdd(&csb[4 * t + 1], a0y);
  atomicAdd(&csb[4 * t + 2], a0z);
  atomicAdd(&csb[4 * t + 3], a0w);
  atomicAdd(&csb[1024 + 4 * t + 0], a1x);
  atomicAdd(&csb[1024 + 4 * t + 1], a1y);
  atomicAdd(&csb[1024 + 4 * t + 2], a1z);
  atomicAdd(&csb[1024 + 4 * t + 3], a1w);
}

// out[b,d] = sum_k cs[b,k] * x[b,k,d]
__global__ __launch_bounds__(512) void out_kernel(
    const float* __restrict__ x, const float* __restrict__ cs,
    float* __restrict__ out) {
  const int b = blockIdx.y;
  const int k0 = blockIdx.x * 128;
  const int d = threadIdx.x;
  const float* xbat = x + (size_t)b * S_ * D_;
  const float* csb = cs + b * S_;
  float acc = 0.f;
  for (int k = k0; k < k0 + 128; k++)
    acc += csb[k] * xbat[(size_t)k * D_ + d];
  atomicAdd(&out[b * D_ + d], acc);
}

extern "C" void kernel_launch(void* const* d_in, const int* in_sizes, int n_in,
                              void* d_out, int out_size, void* d_ws, size_t ws_size,
                              hipStream_t stream) {
  const float* x = (const float*)d_in[0];
  const int* mask = (const int*)d_in[1];
  float* out = (float*)d_out;
  float* p = out + B_ * D_;  // p_attn region, [B][S][S]

  // workspace layout: xb (bf16 x, 16MB) | Z (64KB) | cs (64KB)
  unsigned short* xb = (unsigned short*)d_ws;
  float* Z = (float*)((char*)d_ws + (size_t)B_ * S_ * D_ * 2);
  float* cs = Z + B_ * S_;

  hipMemsetAsync(Z, 0, 2 * (size_t)B_ * S_ * sizeof(float), stream);
  hipMemsetAsync(out, 0, (size_t)B_ * D_ * sizeof(float), stream);

  convert_kernel<<<2048, 256, 0, stream>>>(x, xb, B_ * S_ * D_ / 4);
  gemm_exp_kernel<<<dim3(S_ / 128, S_ / 128, B_), 256, 0, stream>>>(xb, mask, p, Z);
  norm_colsum_kernel<<<dim3(S_ / 16, B_), 256, 0, stream>>>(p, Z, cs);
  out_kernel<<<dim3(S_ / 128, B_), 512, 0, stream>>>(x, cs, out);
}

// Round 2
// 382.634 us; speedup vs baseline: 1.2176x; 1.2176x over previous
//
#include <hip/hip_runtime.h>
#include <cstdint>
#include <cstddef>

#define B_ 8
#define S_ 2048
#define D_ 512

typedef __attribute__((ext_vector_type(8))) short short8;
typedef __attribute__((ext_vector_type(4))) float f32x4;

// f32 -> bf16 round-to-nearest-even
__device__ inline unsigned short f2bf(float f) {
  unsigned u = __float_as_uint(f);
  u += 0x7FFFu + ((u >> 16) & 1u);
  return (unsigned short)(u >> 16);
}

__global__ void convert_kernel(const float* __restrict__ x,
                               unsigned short* __restrict__ xb, int n4) {
  const float4* x4 = (const float4*)x;
  ushort4* o4 = (ushort4*)xb;
  for (int i = blockIdx.x * blockDim.x + threadIdx.x; i < n4;
       i += gridDim.x * blockDim.x) {
    float4 v = x4[i];
    ushort4 o;
    o.x = f2bf(v.x); o.y = f2bf(v.y); o.z = f2bf(v.z); o.w = f2bf(v.w);
    o4[i] = o;
  }
}

// mask (int32) -> bitmask, byte j covers ints [8j, 8j+8)
__global__ void pack_mask_kernel(const int* __restrict__ mask,
                                 unsigned char* __restrict__ bm, int nbytes) {
  for (int j = blockIdx.x * blockDim.x + threadIdx.x; j < nbytes;
       j += gridDim.x * blockDim.x) {
    const int4* m4 = (const int4*)mask + 2 * (size_t)j;
    int4 a = m4[0], b = m4[1];
    unsigned byte = (unsigned)(a.x != 0) | ((unsigned)(a.y != 0) << 1) |
                    ((unsigned)(a.z != 0) << 2) | ((unsigned)(a.w != 0) << 3) |
                    ((unsigned)(b.x != 0) << 4) | ((unsigned)(b.y != 0) << 5) |
                    ((unsigned)(b.z != 0) << 6) | ((unsigned)(b.w != 0) << 7);
    bm[j] = (unsigned char)byte;
  }
}

#define GLDS(g, l) __builtin_amdgcn_global_load_lds( \
    (const __attribute__((address_space(1))) void*)(g), \
    (__attribute__((address_space(3))) void*)(l), 16, 0, 0)

// Pass B (WRITE_P=false): row sums Z only (atomics).
// Pass C (WRITE_P=true):  recompute, write p = u/Z, accumulate column sums.
// LDS A/B tiles are XOR-swizzled (col8 ^= row&7) via pre-swizzled global
// source (linear global_load_lds dest) + swizzled ds_read.
template <bool WRITE_P>
__global__ __launch_bounds__(256) void gemm_pass(
    const unsigned short* __restrict__ xb, const unsigned char* __restrict__ bm,
    float* __restrict__ pbuf, float* __restrict__ Z, float* __restrict__ cs) {
  __shared__ unsigned short At[128 * 64];
  __shared__ unsigned short Bt[128 * 64];
  __shared__ unsigned char mrow[128 * 16];  // bit tile: 128 rows x 128 cols
  __shared__ float zl[128];                 // 1/Z per row (pass C)

  const int b = blockIdx.z;
  const int qt = blockIdx.y;
  const int kt = blockIdx.x;
  const int tid = threadIdx.x;
  const int wid = tid >> 6;
  const int lane = tid & 63;
  const int l15 = lane & 15;
  const int l7 = lane & 7;
  const int lg = lane >> 4;  // 0..3

  const unsigned short* xbat = xb + (size_t)b * S_ * D_;
  const unsigned short* aglob = xbat + (size_t)qt * 128 * D_;
  const unsigned short* bglob = xbat + (size_t)kt * 128 * D_;

  // stage bit tile (and 1/Z for pass C)
  if (tid < 128) {
    *(uint4*)&mrow[tid * 16] =
        *(const uint4*)(bm + ((size_t)b * S_ + qt * 128 + tid) * (S_ / 8) +
                        kt * 16);
    if (WRITE_P) zl[tid] = 1.0f / Z[b * S_ + qt * 128 + tid];
  }

  f32x4 acc[4][4] = {};

  const int wr = (wid >> 1) * 64;  // wave row offset within 128-tile
  const int wc = (wid & 1) * 64;   // wave col offset

  for (int k0 = 0; k0 < D_; k0 += 64) {
    __syncthreads();  // protect LDS from previous iteration's readers
    #pragma unroll
    for (int i = 0; i < 4; i++) {
      int c = i * 256 + tid;           // 16B slot index, wave-linear dest
      int row = c >> 3;
      int col8 = (c & 7) ^ (row & 7);  // inverse-swizzled source chunk
      GLDS(aglob + row * D_ + k0 + col8 * 8, &At[c * 8]);
      GLDS(bglob + row * D_ + k0 + col8 * 8, &Bt[c * 8]);
    }
    __syncthreads();  // drains vmcnt -> LDS tiles valid
    #pragma unroll
    for (int ks8 = 0; ks8 < 8; ks8 += 4) {  // K-slice of 32 (4 chunks)
      const int kc8 = ks8 + lg;
      short8 av[4], bv[4];
      #pragma unroll
      for (int m = 0; m < 4; m++) {
        int row = wr + m * 16 + l15;  // row&7 == l7
        av[m] = *(const short8*)&At[row * 64 + ((kc8 ^ l7) << 3)];
      }
      #pragma unroll
      for (int n = 0; n < 4; n++) {
        int row = wc + n * 16 + l15;
        bv[n] = *(const short8*)&Bt[row * 64 + ((kc8 ^ l7) << 3)];
      }
      #pragma unroll
      for (int m = 0; m < 4; m++)
        #pragma unroll
        for (int n = 0; n < 4; n++)
          acc[m][n] = __builtin_amdgcn_mfma_f32_16x16x32_bf16(
              av[m], bv[n], acc[m][n], 0, 0, 0);
    }
  }
  __syncthreads();  // epilogue reads mrow/zl; also all MFMA done

  const float inv_sqrt_d = 0.04419417382415922f;  // 1/sqrt(512)
  float* pbat = pbuf + (size_t)b * S_ * S_;
  float* Zb = Z + b * S_;
  float* csb = cs + b * S_;
  float csum[4] = {0.f, 0.f, 0.f, 0.f};

  #pragma unroll
  for (int m = 0; m < 4; m++) {
    float rsum[4] = {0.f, 0.f, 0.f, 0.f};
    #pragma unroll
    for (int r = 0; r < 4; r++) {
      const int trow = wr + m * 16 + lg * 4 + r;  // tile-local row
      const uint2 mb = *(const uint2*)&mrow[trow * 16 + (wc >> 3)];
      const float zinv = WRITE_P ? zl[trow] : 0.f;
      #pragma unroll
      for (int n = 0; n < 4; n++) {
        const int idx = n * 16 + l15;  // col within wave's 64-col span
        const unsigned bit =
            (n < 2) ? (mb.x >> idx) : (mb.y >> (idx - 32));
        float u = 0.0f;
        if (bit & 1u)
          u = __expf(__expf(acc[m][n][r]) * inv_sqrt_d);
        if (WRITE_P) {
          float p = u * zinv;
          pbat[(size_t)(qt * 128 + trow) * S_ + kt * 128 + wc + n * 16 + l15] = p;
          csum[n] += p;
        } else {
          rsum[r] += u;
        }
      }
    }
    if (!WRITE_P) {
      // reduce across the 16 lanes sharing a row (l15 spans cols)
      #pragma unroll
      for (int r = 0; r < 4; r++) {
        float v = rsum[r];
        v += __shfl_xor(v, 1);
        v += __shfl_xor(v, 2);
        v += __shfl_xor(v, 4);
        v += __shfl_xor(v, 8);
        if (l15 == 0)
          atomicAdd(&Zb[qt * 128 + wr + m * 16 + lg * 4 + r], v);
      }
    }
  }
  if (WRITE_P) {
    // column sums: reduce across the 4 row-groups (lanes differing in lane>>4)
    #pragma unroll
    for (int n = 0; n < 4; n++) {
      float v = csum[n];
      v += __shfl_xor(v, 16);
      v += __shfl_xor(v, 32);
      if (lg == 0)
        atomicAdd(&csb[kt * 128 + wc + n * 16 + l15], v);
    }
  }
}

// out[b,d] = sum_k cs[b,k] * x[b,k,d]
__global__ __launch_bounds__(512) void out_kernel(
    const float* __restrict__ x, const float* __restrict__ cs,
    float* __restrict__ out) {
  const int b = blockIdx.y;
  const int k0 = blockIdx.x * 128;
  const int d = threadIdx.x;
  const float* xbat = x + (size_t)b * S_ * D_;
  const float* csb = cs + b * S_;
  float acc = 0.f;
  for (int k = k0; k < k0 + 128; k++)
    acc += csb[k] * xbat[(size_t)k * D_ + d];
  atomicAdd(&out[b * D_ + d], acc);
}

extern "C" void kernel_launch(void* const* d_in, const int* in_sizes, int n_in,
                              void* d_out, int out_size, void* d_ws, size_t ws_size,
                              hipStream_t stream) {
  const float* x = (const float*)d_in[0];
  const int* mask = (const int*)d_in[1];
  float* out = (float*)d_out;
  float* p = out + B_ * D_;  // p_attn region, [B][S][S]

  // workspace: xb (bf16 x, 16MB) | bm (bitmask, 4MB) | Z (64KB) | cs (64KB)
  unsigned short* xb = (unsigned short*)d_ws;
  unsigned char* bm = (unsigned char*)d_ws + (size_t)B_ * S_ * D_ * 2;
  float* Z = (float*)(bm + (size_t)B_ * S_ * (S_ / 8));
  float* cs = Z + B_ * S_;

  hipMemsetAsync(Z, 0, 2 * (size_t)B_ * S_ * sizeof(float), stream);
  hipMemsetAsync(out, 0, (size_t)B_ * D_ * sizeof(float), stream);

  convert_kernel<<<2048, 256, 0, stream>>>(x, xb, B_ * S_ * D_ / 4);
  pack_mask_kernel<<<2048, 256, 0, stream>>>(mask, bm, B_ * S_ * (S_ / 8));
  gemm_pass<false><<<dim3(S_ / 128, S_ / 128, B_), 256, 0, stream>>>(
      xb, bm, p, Z, cs);
  gemm_pass<true><<<dim3(S_ / 128, S_ / 128, B_), 256, 0, stream>>>(
      xb, bm, p, Z, cs);
  out_kernel<<<dim3(S_ / 128, B_), 512, 0, stream>>>(x, cs, out);
}

// Round 3
// 374.127 us; speedup vs baseline: 1.2453x; 1.0227x over previous
//
#include <hip/hip_runtime.h>
#include <cstdint>
#include <cstddef>

#define B_ 8
#define S_ 2048
#define D_ 512

typedef __attribute__((ext_vector_type(8))) short short8;
typedef __attribute__((ext_vector_type(4))) float f32x4;

// f32 -> bf16 round-to-nearest-even
__device__ inline unsigned short f2bf(float f) {
  unsigned u = __float_as_uint(f);
  u += 0x7FFFu + ((u >> 16) & 1u);
  return (unsigned short)(u >> 16);
}

// Fused streaming prep: x -> bf16, mask -> bitmask (byte j covers ints [8j,8j+8))
__global__ __launch_bounds__(256) void prep_kernel(
    const float* __restrict__ x, unsigned short* __restrict__ xb,
    const int* __restrict__ mask, unsigned char* __restrict__ bm) {
  const int tid = blockIdx.x * blockDim.x + threadIdx.x;
  const int nth = gridDim.x * blockDim.x;
  const float4* x4 = (const float4*)x;
  ushort4* o4 = (ushort4*)xb;
  for (int i = tid; i < B_ * S_ * D_ / 4; i += nth) {
    float4 v = x4[i];
    ushort4 o;
    o.x = f2bf(v.x); o.y = f2bf(v.y); o.z = f2bf(v.z); o.w = f2bf(v.w);
    o4[i] = o;
  }
  for (int j = tid; j < B_ * S_ * S_ / 8; j += nth) {
    const int4* m4 = (const int4*)mask + 2 * (size_t)j;
    int4 a = m4[0], b = m4[1];
    unsigned byte = (unsigned)(a.x != 0) | ((unsigned)(a.y != 0) << 1) |
                    ((unsigned)(a.z != 0) << 2) | ((unsigned)(a.w != 0) << 3) |
                    ((unsigned)(b.x != 0) << 4) | ((unsigned)(b.y != 0) << 5) |
                    ((unsigned)(b.z != 0) << 6) | ((unsigned)(b.w != 0) << 7);
    bm[j] = (unsigned char)byte;
  }
}

#define GLDS(g, l) __builtin_amdgcn_global_load_lds( \
    (const __attribute__((address_space(1))) void*)(g), \
    (__attribute__((address_space(3))) void*)(l), 16, 0, 0)

// Single GEMM pass: u = mask ? exp(exp(s)/sqrt(D)) : 0 written unnormalized,
// row sums accumulated into Z via atomics. LDS A/B tiles XOR-swizzled
// (col8 ^= row&7) via pre-swizzled global source + swizzled ds_read.
// 1-D grid with XCD swizzle: each XCD owns one batch (4MB xb fits its L2).
__global__ __launch_bounds__(256) void gemm_u_kernel(
    const unsigned short* __restrict__ xb, const unsigned char* __restrict__ bm,
    float* __restrict__ ubuf, float* __restrict__ Z) {
  __shared__ unsigned short At[128 * 64];
  __shared__ unsigned short Bt[128 * 64];
  __shared__ unsigned char mrow[128 * 16];  // bit tile: 128 rows x 128 cols

  const int logical = (blockIdx.x & 7) * 256 + (blockIdx.x >> 3);
  const int b = logical >> 8;
  const int qt = (logical >> 4) & 15;
  const int kt = logical & 15;
  const int tid = threadIdx.x;
  const int wid = tid >> 6;
  const int lane = tid & 63;
  const int l15 = lane & 15;
  const int l7 = lane & 7;
  const int lg = lane >> 4;  // 0..3

  const unsigned short* xbat = xb + (size_t)b * S_ * D_;
  const unsigned short* aglob = xbat + (size_t)qt * 128 * D_;
  const unsigned short* bglob = xbat + (size_t)kt * 128 * D_;

  // stage bit tile
  if (tid < 128) {
    *(uint4*)&mrow[tid * 16] =
        *(const uint4*)(bm + ((size_t)b * S_ + qt * 128 + tid) * (S_ / 8) +
                        kt * 16);
  }

  f32x4 acc[4][4] = {};

  const int wr = (wid >> 1) * 64;  // wave row offset within 128-tile
  const int wc = (wid & 1) * 64;   // wave col offset

  for (int k0 = 0; k0 < D_; k0 += 64) {
    __syncthreads();  // protect LDS from previous iteration's readers
    #pragma unroll
    for (int i = 0; i < 4; i++) {
      int c = i * 256 + tid;           // 16B slot index, wave-linear dest
      int row = c >> 3;
      int col8 = (c & 7) ^ (row & 7);  // inverse-swizzled source chunk
      GLDS(aglob + row * D_ + k0 + col8 * 8, &At[c * 8]);
      GLDS(bglob + row * D_ + k0 + col8 * 8, &Bt[c * 8]);
    }
    __syncthreads();  // drains vmcnt -> LDS tiles valid
    #pragma unroll
    for (int ks8 = 0; ks8 < 8; ks8 += 4) {  // K-slice of 32 (4 chunks)
      const int kc8 = ks8 + lg;
      short8 av[4], bv[4];
      #pragma unroll
      for (int m = 0; m < 4; m++) {
        int row = wr + m * 16 + l15;  // row&7 == l7
        av[m] = *(const short8*)&At[row * 64 + ((kc8 ^ l7) << 3)];
      }
      #pragma unroll
      for (int n = 0; n < 4; n++) {
        int row = wc + n * 16 + l15;
        bv[n] = *(const short8*)&Bt[row * 64 + ((kc8 ^ l7) << 3)];
      }
      #pragma unroll
      for (int m = 0; m < 4; m++)
        #pragma unroll
        for (int n = 0; n < 4; n++)
          acc[m][n] = __builtin_amdgcn_mfma_f32_16x16x32_bf16(
              av[m], bv[n], acc[m][n], 0, 0, 0);
    }
  }
  __syncthreads();  // all MFMA done; mrow stable

  const float inv_sqrt_d = 0.04419417382415922f;  // 1/sqrt(512)
  float* ubat = ubuf + (size_t)b * S_ * S_;
  float* Zb = Z + b * S_;

  #pragma unroll
  for (int m = 0; m < 4; m++) {
    float rsum[4] = {0.f, 0.f, 0.f, 0.f};
    #pragma unroll
    for (int r = 0; r < 4; r++) {
      const int trow = wr + m * 16 + lg * 4 + r;  // tile-local row
      const uint2 mb = *(const uint2*)&mrow[trow * 16 + (wc >> 3)];
      #pragma unroll
      for (int n = 0; n < 4; n++) {
        const int idx = n * 16 + l15;  // col within wave's 64-col span
        const unsigned bit = (n < 2) ? (mb.x >> idx) : (mb.y >> (idx - 32));
        float u = 0.0f;
        if (bit & 1u)
          u = __expf(__expf(acc[m][n][r]) * inv_sqrt_d);
        ubat[(size_t)(qt * 128 + trow) * S_ + kt * 128 + wc + n * 16 + l15] = u;
        rsum[r] += u;
      }
    }
    // reduce across the 16 lanes sharing a row (l15 spans cols)
    #pragma unroll
    for (int r = 0; r < 4; r++) {
      float v = rsum[r];
      v += __shfl_xor(v, 1);
      v += __shfl_xor(v, 2);
      v += __shfl_xor(v, 4);
      v += __shfl_xor(v, 8);
      if (l15 == 0)
        atomicAdd(&Zb[qt * 128 + wr + m * 16 + lg * 4 + r], v);
    }
  }
}

// p = u * (1/Z) in place, column sums accumulated into cs via atomics.
__global__ __launch_bounds__(256) void norm_kernel(
    float* __restrict__ p, const float* __restrict__ Z, float* __restrict__ cs) {
  const int b = blockIdx.y;
  const int qc = blockIdx.x;  // 16-row chunk
  const int t = threadIdx.x;
  float4* prow = (float4*)(p + ((size_t)b * S_ + qc * 16) * S_);
  const float* Zb = Z + b * S_ + qc * 16;
  float4 a0 = {0.f, 0.f, 0.f, 0.f};
  float4 a1 = {0.f, 0.f, 0.f, 0.f};
  for (int r = 0; r < 16; r++) {
    float invZ = 1.0f / Zb[r];
    float4 u0 = prow[r * 512 + t];
    float4 u1 = prow[r * 512 + t + 256];
    u0.x *= invZ; u0.y *= invZ; u0.z *= invZ; u0.w *= invZ;
    u1.x *= invZ; u1.y *= invZ; u1.z *= invZ; u1.w *= invZ;
    prow[r * 512 + t] = u0;
    prow[r * 512 + t + 256] = u1;
    a0.x += u0.x; a0.y += u0.y; a0.z += u0.z; a0.w += u0.w;
    a1.x += u1.x; a1.y += u1.y; a1.z += u1.z; a1.w += u1.w;
  }
  float* csb = cs + b * S_;
  atomicAdd(&csb[4 * t + 0], a0.x);
  atomicAdd(&csb[4 * t + 1], a0.y);
  atomicAdd(&csb[4 * t + 2], a0.z);
  atomicAdd(&csb[4 * t + 3], a0.w);
  atomicAdd(&csb[1024 + 4 * t + 0], a1.x);
  atomicAdd(&csb[1024 + 4 * t + 1], a1.y);
  atomicAdd(&csb[1024 + 4 * t + 2], a1.z);
  atomicAdd(&csb[1024 + 4 * t + 3], a1.w);
}

// out[b,d] = sum_k cs[b,k] * x[b,k,d]  (f32 x for precision)
__global__ __launch_bounds__(512) void out_kernel(
    const float* __restrict__ x, const float* __restrict__ cs,
    float* __restrict__ out) {
  const int b = blockIdx.y;
  const int k0 = blockIdx.x * 32;
  const int d = threadIdx.x;
  const float* xbat = x + (size_t)b * S_ * D_;
  const float* csb = cs + b * S_;
  float acc = 0.f;
  #pragma unroll 8
  for (int k = k0; k < k0 + 32; k++)
    acc += csb[k] * xbat[(size_t)k * D_ + d];
  atomicAdd(&out[b * D_ + d], acc);
}

extern "C" void kernel_launch(void* const* d_in, const int* in_sizes, int n_in,
                              void* d_out, int out_size, void* d_ws, size_t ws_size,
                              hipStream_t stream) {
  const float* x = (const float*)d_in[0];
  const int* mask = (const int*)d_in[1];
  float* out = (float*)d_out;
  float* p = out + B_ * D_;  // p_attn region, [B][S][S]

  // workspace: xb (bf16 x, 16MB) | bm (bitmask, 4MB) | Z (64KB) | cs (64KB)
  unsigned short* xb = (unsigned short*)d_ws;
  unsigned char* bm = (unsigned char*)d_ws + (size_t)B_ * S_ * D_ * 2;
  float* Z = (float*)(bm + (size_t)B_ * S_ * (S_ / 8));
  float* cs = Z + B_ * S_;

  hipMemsetAsync(Z, 0, 2 * (size_t)B_ * S_ * sizeof(float), stream);  // Z + cs
  hipMemsetAsync(out, 0, (size_t)B_ * D_ * sizeof(float), stream);

  prep_kernel<<<2048, 256, 0, stream>>>(x, xb, mask, bm);
  gemm_u_kernel<<<2048, 256, 0, stream>>>(xb, bm, p, Z);
  norm_kernel<<<dim3(S_ / 16, B_), 256, 0, stream>>>(p, Z, cs);
  out_kernel<<<dim3(S_ / 32, B_), 512, 0, stream>>>(x, cs, out);
}

// Round 9
// 362.859 us; speedup vs baseline: 1.2840x; 1.0311x over previous
//
#include <hip/hip_runtime.h>
#include <cstdint>
#include <cstddef>

#define B_ 8
#define S_ 2048
#define D_ 512

typedef __attribute__((ext_vector_type(8))) short short8;
typedef __attribute__((ext_vector_type(4))) float f32x4;

// f32 -> bf16 round-to-nearest-even
__device__ inline unsigned short f2bf(float f) {
  unsigned u = __float_as_uint(f);
  u += 0x7FFFu + ((u >> 16) & 1u);
  return (unsigned short)(u >> 16);
}

// x -> bf16 only (mask handled inside gemm now)
__global__ __launch_bounds__(256) void convert_kernel(
    const float* __restrict__ x, unsigned short* __restrict__ xb) {
  const float4* x4 = (const float4*)x;
  ushort4* o4 = (ushort4*)xb;
  const int nth = gridDim.x * blockDim.x;
  for (int i = blockIdx.x * blockDim.x + threadIdx.x; i < B_ * S_ * D_ / 4;
       i += nth) {
    float4 v = x4[i];
    ushort4 o;
    o.x = f2bf(v.x); o.y = f2bf(v.y); o.z = f2bf(v.z); o.w = f2bf(v.w);
    o4[i] = o;
  }
}

#define GLDS(g, l) __builtin_amdgcn_global_load_lds( \
    (const __attribute__((address_space(1))) void*)(g), \
    (__attribute__((address_space(3))) void*)(l), 16, 0, 0)

__device__ inline unsigned pack8(int4 a, int4 b) {
  return (unsigned)(a.x != 0) | ((unsigned)(a.y != 0) << 1) |
         ((unsigned)(a.z != 0) << 2) | ((unsigned)(a.w != 0) << 3) |
         ((unsigned)(b.x != 0) << 4) | ((unsigned)(b.y != 0) << 5) |
         ((unsigned)(b.z != 0) << 6) | ((unsigned)(b.w != 0) << 7);
}

// GEMM tile: u = mask ? exp(exp(s)/sqrt(D)) : 0 (unnormalized) -> ubuf,
// row-sum atomics into Z.  Raw int32 mask read + bit-pack fused in-kernel
// (mask tile is consumed by exactly this one block).  LDS A/B XOR-swizzled
// via pre-swizzled global source + swizzled ds_read (proven R2/R3 body).
// 1-D grid, XCD (bid&7) == batch -> xb panel L2-resident.
__global__ __launch_bounds__(256, 4) void gemm_u_kernel(
    const unsigned short* __restrict__ xb, const int* __restrict__ mask,
    float* __restrict__ ubuf, float* __restrict__ Z) {
  __shared__ unsigned short At[128 * 64];
  __shared__ unsigned short Bt[128 * 64];
  __shared__ unsigned char mrow[128 * 16];  // bit tile: 128 rows x 128 cols

  const int logical = (blockIdx.x & 7) * 256 + (blockIdx.x >> 3);
  const int b = logical >> 8;
  const int qt = (logical >> 4) & 15;
  const int kt = logical & 15;
  const int tid = threadIdx.x;
  const int wid = tid >> 6;
  const int lane = tid & 63;
  const int l15 = lane & 15;
  const int l7 = lane & 7;
  const int lg = lane >> 4;  // 0..3
  const int wr = (wid >> 1) * 64;
  const int wc = (wid & 1) * 64;
  const float inv_sqrt_d = 0.04419417382415922f;  // 1/sqrt(512)

  const unsigned short* xbat = xb + (size_t)b * S_ * D_;
  const unsigned short* aglob = xbat + (size_t)qt * 128 * D_;
  const unsigned short* bglob = xbat + (size_t)kt * 128 * D_;

  // ---- fused mask read + bit-pack: thread t owns row t>>1, 64-col half t&1.
  // 16 ints (4 x int4) per round, 4 rounds = 64 ints -> 8 bytes.
  {
    const int trow = tid >> 1;
    const int half = tid & 1;
    const int4* mg = (const int4*)(mask + ((size_t)b * S_ + qt * 128 + trow) * S_ +
                                   kt * 128 + half * 64);
    unsigned lo = 0, hi = 0;
    #pragma unroll
    for (int c4 = 0; c4 < 4; c4++) {
      int4 a = mg[c4 * 4 + 0];
      int4 bb = mg[c4 * 4 + 1];
      int4 c = mg[c4 * 4 + 2];
      int4 d = mg[c4 * 4 + 3];
      unsigned by0 = pack8(a, bb);
      unsigned by1 = pack8(c, d);
      if (c4 < 2) {
        lo |= (by0 << (c4 * 16)) | (by1 << (c4 * 16 + 8));
      } else {
        hi |= (by0 << ((c4 - 2) * 16)) | (by1 << ((c4 - 2) * 16 + 8));
      }
    }
    uint2 pk; pk.x = lo; pk.y = hi;
    *(uint2*)&mrow[trow * 16 + half * 8] = pk;
  }

  f32x4 acc[4][4] = {};

  for (int k0 = 0; k0 < D_; k0 += 64) {
    __syncthreads();  // protect LDS from previous iteration's readers
    #pragma unroll
    for (int i = 0; i < 4; i++) {
      int c = i * 256 + tid;           // 16B slot, wave-linear dest
      int row = c >> 3;
      int col8 = (c & 7) ^ (row & 7);  // inverse-swizzled source chunk
      GLDS(aglob + row * D_ + k0 + col8 * 8, &At[c * 8]);
      GLDS(bglob + row * D_ + k0 + col8 * 8, &Bt[c * 8]);
    }
    __syncthreads();  // drains vmcnt -> LDS tiles valid
    #pragma unroll
    for (int ks8 = 0; ks8 < 8; ks8 += 4) {  // K-slice of 32 (4 chunks)
      const int kc8 = ks8 + lg;
      short8 av[4], bv[4];
      #pragma unroll
      for (int m = 0; m < 4; m++) {
        int row = wr + m * 16 + l15;  // row&7 == l7
        av[m] = *(const short8*)&At[row * 64 + ((kc8 ^ l7) << 3)];
      }
      #pragma unroll
      for (int n = 0; n < 4; n++) {
        int row = wc + n * 16 + l15;
        bv[n] = *(const short8*)&Bt[row * 64 + ((kc8 ^ l7) << 3)];
      }
      #pragma unroll
      for (int m = 0; m < 4; m++)
        #pragma unroll
        for (int n = 0; n < 4; n++)
          acc[m][n] = __builtin_amdgcn_mfma_f32_16x16x32_bf16(
              av[m], bv[n], acc[m][n], 0, 0, 0);
    }
  }
  __syncthreads();  // all MFMA done; mrow stable

  float* ubat = ubuf + (size_t)b * S_ * S_;
  float* Zb = Z + b * S_;

  #pragma unroll
  for (int m = 0; m < 4; m++) {
    float rsum[4] = {0.f, 0.f, 0.f, 0.f};
    #pragma unroll
    for (int r = 0; r < 4; r++) {
      const int trow = wr + m * 16 + lg * 4 + r;  // tile-local row
      const uint2 mb = *(const uint2*)&mrow[trow * 16 + (wc >> 3)];
      #pragma unroll
      for (int n = 0; n < 4; n++) {
        const int idx = n * 16 + l15;
        const unsigned bit = (n < 2) ? (mb.x >> idx) : (mb.y >> (idx - 32));
        float u = 0.0f;
        if (bit & 1u)
          u = __expf(__expf(acc[m][n][r]) * inv_sqrt_d);
        ubat[(size_t)(qt * 128 + trow) * S_ + kt * 128 + wc + n * 16 + l15] = u;
        rsum[r] += u;
      }
    }
    #pragma unroll
    for (int r = 0; r < 4; r++) {
      float v = rsum[r];
      v += __shfl_xor(v, 1);
      v += __shfl_xor(v, 2);
      v += __shfl_xor(v, 4);
      v += __shfl_xor(v, 8);
      if (l15 == 0)
        atomicAdd(&Zb[qt * 128 + wr + m * 16 + lg * 4 + r], v);
    }
  }
}

// Column-strip normalize: block owns (b, 128-col chunk, row-half).
// p = u * (1/Z) in place (NT); column sums block-local via LDS reduce,
// one atomic per column per block (2-way contention only).
__global__ __launch_bounds__(256) void norm_kernel(
    float* __restrict__ p, const float* __restrict__ Z, float* __restrict__ cs) {
  const int b = blockIdx.y;
  const int cc = blockIdx.x >> 1;  // col chunk (128 cols)
  const int rh = blockIdx.x & 1;   // row half (1024 rows)
  const int t = threadIdx.x;
  const int s = t & 31;            // f32x4 slot within chunk
  const int g = t >> 5;            // row group 0..7
  const int c0 = cc * 128;
  __shared__ float red[8][128];

  f32x4* p4 = (f32x4*)(p + (size_t)b * S_ * S_);
  const float* Zb = Z + b * S_;
  float s0 = 0.f, s1 = 0.f, s2 = 0.f, s3 = 0.f;
  const int qbase = rh * 1024 + g;
  for (int i = 0; i < 128; i++) {
    const int q = qbase + i * 8;
    const float invZ = 1.0f / Zb[q];
    f32x4* addr = &p4[(size_t)q * (S_ / 4) + (c0 >> 2) + s];
    f32x4 u = __builtin_nontemporal_load(addr);
    u *= invZ;
    __builtin_nontemporal_store(u, addr);
    s0 += u.x; s1 += u.y; s2 += u.z; s3 += u.w;
  }
  red[g][s * 4 + 0] = s0;
  red[g][s * 4 + 1] = s1;
  red[g][s * 4 + 2] = s2;
  red[g][s * 4 + 3] = s3;
  __syncthreads();
  if (t < 128) {
    float v = 0.f;
    #pragma unroll
    for (int gg = 0; gg < 8; gg++) v += red[gg][t];
    atomicAdd(&cs[b * S_ + c0 + t], v);
  }
}

// out[b,d] = sum_k cs[b,k] * x[b,k,d]  (f32 x for precision)
__global__ __launch_bounds__(256) void out_kernel(
    const float* __restrict__ x, const float* __restrict__ cs,
    float* __restrict__ out) {
  const int b = blockIdx.x & 7;
  const int k0 = (blockIdx.x >> 3) * 64;
  const int tid = threadIdx.x;
  const float* xbat = x + (size_t)b * S_ * D_;
  const float* csb = cs + b * S_;
  float a0 = 0.f, a1 = 0.f;
  #pragma unroll 4
  for (int k = k0; k < k0 + 64; k++) {
    float c = csb[k];
    a0 += c * xbat[(size_t)k * D_ + tid];
    a1 += c * xbat[(size_t)k * D_ + tid + 256];
  }
  atomicAdd(&out[b * D_ + tid], a0);
  atomicAdd(&out[b * D_ + tid + 256], a1);
}

extern "C" void kernel_launch(void* const* d_in, const int* in_sizes, int n_in,
                              void* d_out, int out_size, void* d_ws, size_t ws_size,
                              hipStream_t stream) {
  const float* x = (const float*)d_in[0];
  const int* mask = (const int*)d_in[1];
  float* out = (float*)d_out;
  float* p = out + B_ * D_;  // p_attn region, [B][S][S]

  // workspace: xb (bf16 x, 16MB) | Z (64KB) | cs (64KB)
  unsigned short* xb = (unsigned short*)d_ws;
  float* Z = (float*)((char*)d_ws + (size_t)B_ * S_ * D_ * 2);
  float* cs = Z + B_ * S_;

  hipMemsetAsync(Z, 0, 2 * (size_t)B_ * S_ * sizeof(float), stream);  // Z + cs
  hipMemsetAsync(out, 0, (size_t)B_ * D_ * sizeof(float), stream);

  convert_kernel<<<1024, 256, 0, stream>>>(x, xb);
  gemm_u_kernel<<<2048, 256, 0, stream>>>(xb, mask, p, Z);
  norm_kernel<<<dim3(32, B_), 256, 0, stream>>>(p, Z, cs);
  out_kernel<<<256, 256, 0, stream>>>(x, cs, out);
}

// Round 10
// 358.472 us; speedup vs baseline: 1.2997x; 1.0122x over previous
//
#include <hip/hip_runtime.h>
#include <cstdint>
#include <cstddef>

#define B_ 8
#define S_ 2048
#define D_ 512

typedef __attribute__((ext_vector_type(8))) short short8;
typedef __attribute__((ext_vector_type(4))) float f32x4;

// f32 -> bf16 round-to-nearest-even
__device__ inline unsigned short f2bf(float f) {
  unsigned u = __float_as_uint(f);
  u += 0x7FFFu + ((u >> 16) & 1u);
  return (unsigned short)(u >> 16);
}

// x -> bf16 only (mask handled inside gemm)
__global__ __launch_bounds__(256) void convert_kernel(
    const float* __restrict__ x, unsigned short* __restrict__ xb) {
  const float4* x4 = (const float4*)x;
  ushort4* o4 = (ushort4*)xb;
  const int nth = gridDim.x * blockDim.x;
  for (int i = blockIdx.x * blockDim.x + threadIdx.x; i < B_ * S_ * D_ / 4;
       i += nth) {
    float4 v = x4[i];
    ushort4 o;
    o.x = f2bf(v.x); o.y = f2bf(v.y); o.z = f2bf(v.z); o.w = f2bf(v.w);
    o4[i] = o;
  }
}

#define GLDS(g, l) __builtin_amdgcn_global_load_lds( \
    (const __attribute__((address_space(1))) void*)(g), \
    (__attribute__((address_space(3))) void*)(l), 16, 0, 0)

__device__ inline unsigned pack8(int4 a, int4 b) {
  return (unsigned)(a.x != 0) | ((unsigned)(a.y != 0) << 1) |
         ((unsigned)(a.z != 0) << 2) | ((unsigned)(a.w != 0) << 3) |
         ((unsigned)(b.x != 0) << 4) | ((unsigned)(b.y != 0) << 5) |
         ((unsigned)(b.z != 0) << 6) | ((unsigned)(b.w != 0) << 7);
}

// GEMM tile: u = mask ? exp(exp(s)/sqrt(D)) : 0 (unnormalized) -> ubuf,
// row-sum atomics into Z.  Raw int32 mask read + bit-pack fused in-kernel.
// LDS A/B XOR-swizzled via pre-swizzled global source + swizzled ds_read.
// 1-D grid, XCD (bid&7) == batch -> xb panel L2-resident.  (Proven R9 body.)
__global__ __launch_bounds__(256, 4) void gemm_u_kernel(
    const unsigned short* __restrict__ xb, const int* __restrict__ mask,
    float* __restrict__ ubuf, float* __restrict__ Z) {
  __shared__ unsigned short At[128 * 64];
  __shared__ unsigned short Bt[128 * 64];
  __shared__ unsigned char mrow[128 * 16];  // bit tile: 128 rows x 128 cols

  const int logical = (blockIdx.x & 7) * 256 + (blockIdx.x >> 3);
  const int b = logical >> 8;
  const int qt = (logical >> 4) & 15;
  const int kt = logical & 15;
  const int tid = threadIdx.x;
  const int wid = tid >> 6;
  const int lane = tid & 63;
  const int l15 = lane & 15;
  const int l7 = lane & 7;
  const int lg = lane >> 4;  // 0..3
  const int wr = (wid >> 1) * 64;
  const int wc = (wid & 1) * 64;
  const float inv_sqrt_d = 0.04419417382415922f;  // 1/sqrt(512)

  const unsigned short* xbat = xb + (size_t)b * S_ * D_;
  const unsigned short* aglob = xbat + (size_t)qt * 128 * D_;
  const unsigned short* bglob = xbat + (size_t)kt * 128 * D_;

  // fused mask read + bit-pack: thread t owns row t>>1, 64-col half t&1.
  {
    const int trow = tid >> 1;
    const int half = tid & 1;
    const int4* mg = (const int4*)(mask + ((size_t)b * S_ + qt * 128 + trow) * S_ +
                                   kt * 128 + half * 64);
    unsigned lo = 0, hi = 0;
    #pragma unroll
    for (int c4 = 0; c4 < 4; c4++) {
      int4 a = mg[c4 * 4 + 0];
      int4 bb = mg[c4 * 4 + 1];
      int4 c = mg[c4 * 4 + 2];
      int4 d = mg[c4 * 4 + 3];
      unsigned by0 = pack8(a, bb);
      unsigned by1 = pack8(c, d);
      if (c4 < 2) {
        lo |= (by0 << (c4 * 16)) | (by1 << (c4 * 16 + 8));
      } else {
        hi |= (by0 << ((c4 - 2) * 16)) | (by1 << ((c4 - 2) * 16 + 8));
      }
    }
    uint2 pk; pk.x = lo; pk.y = hi;
    *(uint2*)&mrow[trow * 16 + half * 8] = pk;
  }

  f32x4 acc[4][4] = {};

  for (int k0 = 0; k0 < D_; k0 += 64) {
    __syncthreads();  // protect LDS from previous iteration's readers
    #pragma unroll
    for (int i = 0; i < 4; i++) {
      int c = i * 256 + tid;           // 16B slot, wave-linear dest
      int row = c >> 3;
      int col8 = (c & 7) ^ (row & 7);  // inverse-swizzled source chunk
      GLDS(aglob + row * D_ + k0 + col8 * 8, &At[c * 8]);
      GLDS(bglob + row * D_ + k0 + col8 * 8, &Bt[c * 8]);
    }
    __syncthreads();  // drains vmcnt -> LDS tiles valid
    #pragma unroll
    for (int ks8 = 0; ks8 < 8; ks8 += 4) {  // K-slice of 32 (4 chunks)
      const int kc8 = ks8 + lg;
      short8 av[4], bv[4];
      #pragma unroll
      for (int m = 0; m < 4; m++) {
        int row = wr + m * 16 + l15;  // row&7 == l7
        av[m] = *(const short8*)&At[row * 64 + ((kc8 ^ l7) << 3)];
      }
      #pragma unroll
      for (int n = 0; n < 4; n++) {
        int row = wc + n * 16 + l15;
        bv[n] = *(const short8*)&Bt[row * 64 + ((kc8 ^ l7) << 3)];
      }
      #pragma unroll
      for (int m = 0; m < 4; m++)
        #pragma unroll
        for (int n = 0; n < 4; n++)
          acc[m][n] = __builtin_amdgcn_mfma_f32_16x16x32_bf16(
              av[m], bv[n], acc[m][n], 0, 0, 0);
    }
  }
  __syncthreads();  // all MFMA done; mrow stable

  float* ubat = ubuf + (size_t)b * S_ * S_;
  float* Zb = Z + b * S_;

  #pragma unroll
  for (int m = 0; m < 4; m++) {
    float rsum[4] = {0.f, 0.f, 0.f, 0.f};
    #pragma unroll
    for (int r = 0; r < 4; r++) {
      const int trow = wr + m * 16 + lg * 4 + r;  // tile-local row
      const uint2 mb = *(const uint2*)&mrow[trow * 16 + (wc >> 3)];
      #pragma unroll
      for (int n = 0; n < 4; n++) {
        const int idx = n * 16 + l15;
        const unsigned bit = (n < 2) ? (mb.x >> idx) : (mb.y >> (idx - 32));
        float u = 0.0f;
        if (bit & 1u)
          u = __expf(__expf(acc[m][n][r]) * inv_sqrt_d);
        ubat[(size_t)(qt * 128 + trow) * S_ + kt * 128 + wc + n * 16 + l15] = u;
        rsum[r] += u;
      }
    }
    #pragma unroll
    for (int r = 0; r < 4; r++) {
      float v = rsum[r];
      v += __shfl_xor(v, 1);
      v += __shfl_xor(v, 2);
      v += __shfl_xor(v, 4);
      v += __shfl_xor(v, 8);
      if (l15 == 0)
        atomicAdd(&Zb[qt * 128 + wr + m * 16 + lg * 4 + r], v);
    }
  }
}

// Column-strip normalize: block owns (b, 128-col chunk, 256-row split).
// 1024 blocks = 4/CU (16 waves/CU) so HBM latency hides under TLP.
// Regular loads (L2-cacheable), NT stores. Column sums block-local via LDS,
// one atomic per column per block (8-way contention).
__global__ __launch_bounds__(256) void norm_kernel(
    float* __restrict__ p, const float* __restrict__ Z, float* __restrict__ cs) {
  const int b = blockIdx.y;
  const int cc = blockIdx.x >> 3;  // col chunk (128 cols), 0..15
  const int rh = blockIdx.x & 7;   // row split (256 rows), 0..7
  const int t = threadIdx.x;
  const int s = t & 31;            // f32x4 slot within chunk
  const int g = t >> 5;            // row group 0..7
  const int c0 = cc * 128;
  __shared__ float red[8][128];

  f32x4* p4 = (f32x4*)(p + (size_t)b * S_ * S_);
  const float* Zb = Z + b * S_;
  float s0 = 0.f, s1 = 0.f, s2 = 0.f, s3 = 0.f;
  const int qbase = rh * 256 + g;
  #pragma unroll 4
  for (int i = 0; i < 32; i++) {
    const int q = qbase + i * 8;
    const float invZ = 1.0f / Zb[q];
    f32x4* addr = &p4[(size_t)q * (S_ / 4) + (c0 >> 2) + s];
    f32x4 u = *addr;
    u *= invZ;
    __builtin_nontemporal_store(u, addr);
    s0 += u.x; s1 += u.y; s2 += u.z; s3 += u.w;
  }
  red[g][s * 4 + 0] = s0;
  red[g][s * 4 + 1] = s1;
  red[g][s * 4 + 2] = s2;
  red[g][s * 4 + 3] = s3;
  __syncthreads();
  if (t < 128) {
    float v = 0.f;
    #pragma unroll
    for (int gg = 0; gg < 8; gg++) v += red[gg][t];
    atomicAdd(&cs[b * S_ + c0 + t], v);
  }
}

// out[b,d] = sum_k cs[b,k] * x[b,k,d]  (f32 x for precision)
__global__ __launch_bounds__(256) void out_kernel(
    const float* __restrict__ x, const float* __restrict__ cs,
    float* __restrict__ out) {
  const int b = blockIdx.x & 7;
  const int k0 = (blockIdx.x >> 3) * 64;
  const int tid = threadIdx.x;
  const float* xbat = x + (size_t)b * S_ * D_;
  const float* csb = cs + b * S_;
  float a0 = 0.f, a1 = 0.f;
  #pragma unroll 4
  for (int k = k0; k < k0 + 64; k++) {
    float c = csb[k];
    a0 += c * xbat[(size_t)k * D_ + tid];
    a1 += c * xbat[(size_t)k * D_ + tid + 256];
  }
  atomicAdd(&out[b * D_ + tid], a0);
  atomicAdd(&out[b * D_ + tid + 256], a1);
}

extern "C" void kernel_launch(void* const* d_in, const int* in_sizes, int n_in,
                              void* d_out, int out_size, void* d_ws, size_t ws_size,
                              hipStream_t stream) {
  const float* x = (const float*)d_in[0];
  const int* mask = (const int*)d_in[1];
  float* out = (float*)d_out;
  float* p = out + B_ * D_;  // p_attn region, [B][S][S]

  // workspace: xb (bf16 x, 16MB) | Z (64KB) | cs (64KB)
  unsigned short* xb = (unsigned short*)d_ws;
  float* Z = (float*)((char*)d_ws + (size_t)B_ * S_ * D_ * 2);
  float* cs = Z + B_ * S_;

  hipMemsetAsync(Z, 0, 2 * (size_t)B_ * S_ * sizeof(float), stream);  // Z + cs
  hipMemsetAsync(out, 0, (size_t)B_ * D_ * sizeof(float), stream);

  convert_kernel<<<1024, 256, 0, stream>>>(x, xb);
  gemm_u_kernel<<<2048, 256, 0, stream>>>(xb, mask, p, Z);
  norm_kernel<<<dim3(128, B_), 256, 0, stream>>>(p, Z, cs);
  out_kernel<<<256, 256, 0, stream>>>(x, cs, out);
}